// Round 1
// baseline (1041.640 us; speedup 1.0000x reference)
//
#include <hip/hip_runtime.h>

#define N_DIM 8192
#define EPS 1e-6f
#define R_STRIP 16                     // rows per fused block
#define NRB (N_DIM / R_STRIP)          // 512 row-strip blocks
#define TPB 1024                       // 16 waves: 1 uint4 (8 cols) per thread per row

typedef float f32x4v __attribute__((ext_vector_type(4)));

// ---------- bf16 helpers (bit-level) ----------
__device__ __forceinline__ float bflo(unsigned u) { return __uint_as_float(u << 16); }
__device__ __forceinline__ float bfhi(unsigned u) { return __uint_as_float(u & 0xffff0000u); }
__device__ __forceinline__ unsigned f2bf_bits(float f) {
    unsigned u = __float_as_uint(f);
    return (u + 0x7fffu + ((u >> 16) & 1u)) >> 16;   // round-to-nearest-even
}
__device__ __forceinline__ float sigmoidf_fast(float x) {
    return 1.f / (1.f + __expf(-x));
}
__device__ __forceinline__ float dot8(uint4 b, float4 c0, float4 c1) {
    return bflo(b.x) * c0.x + bfhi(b.x) * c0.y + bflo(b.y) * c0.z + bfhi(b.y) * c0.w
         + bflo(b.z) * c1.x + bfhi(b.z) * c1.y + bflo(b.w) * c1.z + bfhi(b.w) * c1.w;
}
__device__ __forceinline__ void acc8(float* a, uint4 b, float rr) {
    a[0] += bflo(b.x) * rr; a[1] += bfhi(b.x) * rr;
    a[2] += bflo(b.y) * rr; a[3] += bfhi(b.y) * rr;
    a[4] += bflo(b.z) * rr; a[5] += bfhi(b.z) * rr;
    a[6] += bflo(b.w) * rr; a[7] += bfhi(b.w) * rr;
}
// sigmoid+I, pack 8 to bf16, accumulate rounded sum into t
__device__ __forceinline__ uint4 sig_pack8(float4 x0, float4 x1, int jbase, int row, float& t) {
    float s[8] = { sigmoidf_fast(x0.x), sigmoidf_fast(x0.y), sigmoidf_fast(x0.z), sigmoidf_fast(x0.w),
                   sigmoidf_fast(x1.x), sigmoidf_fast(x1.y), sigmoidf_fast(x1.z), sigmoidf_fast(x1.w) };
    #pragma unroll
    for (int k = 0; k < 8; ++k)
        if (jbase + k == row) s[k] += 1.f;
    unsigned b[8];
    #pragma unroll
    for (int k = 0; k < 8; ++k) {
        b[k] = f2bf_bits(s[k]);
        t += __uint_as_float(b[k] << 16);          // sum the ROUNDED values
    }
    return make_uint4(b[0] | (b[1] << 16), b[2] | (b[3] << 16),
                      b[4] | (b[5] << 16), b[6] | (b[7] << 16));
}

// ---------- k_init: B = bf16(sigmoid+I); fused iteration-1 row norm + col partials ----------
// 1024 threads cache the whole 16-row strip in registers; ONE reduction (2 barriers/block).
__global__ __launch_bounds__(TPB, 4) void k_init(const float* __restrict__ logits,
                                                 unsigned short* __restrict__ B,
                                                 float* __restrict__ r,
                                                 float* __restrict__ partial) {
    __shared__ float sredT[16][16];                 // [wave][row]
    __shared__ float rr[16];
    const int tid = threadIdx.x;
    const int lane = tid & 63, wid = tid >> 6;      // 16 waves
    const int i0 = blockIdx.x * R_STRIP;
    uint4 b[16];
    float t[16];
    #pragma unroll
    for (int q = 0; q < 16; ++q) {
        const int row = i0 + q;
        const f32x4v* l = (const f32x4v*)(logits + (size_t)row * N_DIM);
        const f32x4v xa = __builtin_nontemporal_load(l + 2 * tid);      // read-once: don't cache
        const f32x4v xb = __builtin_nontemporal_load(l + 2 * tid + 1);
        float tl = 0.f;
        b[q] = sig_pack8(make_float4(xa.x, xa.y, xa.z, xa.w),
                         make_float4(xb.x, xb.y, xb.z, xb.w), tid * 8, row, tl);
        t[q] = tl;
        ((uint4*)(B + (size_t)row * N_DIM))[tid] = b[q];
    }
    // one butterfly reduce of all 16 row-partials across the wave (static indexing only)
    #pragma unroll
    for (int off = 32; off > 0; off >>= 1)
        #pragma unroll
        for (int q = 0; q < 16; ++q) t[q] += __shfl_xor(t[q], off, 64);
    if (lane == 0) {
        #pragma unroll
        for (int q = 0; q < 16; ++q) sredT[wid][q] = t[q];
    }
    __syncthreads();
    if (tid < 16) {
        float T = 0.f;
        #pragma unroll
        for (int w = 0; w < 16; ++w) T += sredT[w][tid];
        const float rv = 1.f / (T + EPS);           // r_old = 1
        rr[tid] = rv;
        r[i0 + tid] = rv;
    }
    __syncthreads();
    float a[8];
    #pragma unroll
    for (int k = 0; k < 8; ++k) a[k] = 0.f;
    #pragma unroll
    for (int q = 0; q < 16; ++q) acc8(a, b[q], rr[q]);
    float* p = partial + (size_t)blockIdx.x * N_DIM + tid * 8;
    *(float4*)p       = make_float4(a[0], a[1], a[2], a[3]);
    *(float4*)(p + 4) = make_float4(a[4], a[5], a[6], a[7]);
}

// ---------- k_fused: one full iteration's row step + col partials, ONE pass over B ----------
// All 16 row-loads issued up front (256 B/thread in flight); cvec hoisted to registers once.
__global__ __launch_bounds__(TPB, 4) void k_fused(const unsigned short* __restrict__ B,
                                                  const float* __restrict__ cvec,
                                                  float* __restrict__ r,
                                                  float* __restrict__ partial) {
    __shared__ float sredT[16][16];
    __shared__ float rr[16];
    const int tid = threadIdx.x;
    const int lane = tid & 63, wid = tid >> 6;
    const int i0 = blockIdx.x * R_STRIP;
    const float4 c0 = ((const float4*)cvec)[2 * tid];
    const float4 c1 = ((const float4*)cvec)[2 * tid + 1];
    const uint4* bp = (const uint4*)B + tid;
    uint4 b[16];
    #pragma unroll
    for (int q = 0; q < 16; ++q)
        b[q] = bp[(size_t)(i0 + q) << 10];          // row stride = 1024 uint4
    float t[16];
    #pragma unroll
    for (int q = 0; q < 16; ++q) t[q] = dot8(b[q], c0, c1);
    #pragma unroll
    for (int off = 32; off > 0; off >>= 1)
        #pragma unroll
        for (int q = 0; q < 16; ++q) t[q] += __shfl_xor(t[q], off, 64);
    if (lane == 0) {
        #pragma unroll
        for (int q = 0; q < 16; ++q) sredT[wid][q] = t[q];
    }
    __syncthreads();
    if (tid < 16) {
        float T = 0.f;
        #pragma unroll
        for (int w = 0; w < 16; ++w) T += sredT[w][tid];
        const float rold = r[i0 + tid];
        const float rv = rold / (rold * T + EPS);
        rr[tid] = rv;
        r[i0 + tid] = rv;
    }
    __syncthreads();
    float a[8];
    #pragma unroll
    for (int k = 0; k < 8; ++k) a[k] = 0.f;
    #pragma unroll
    for (int q = 0; q < 16; ++q) acc8(a, b[q], rr[q]);
    float* p = partial + (size_t)blockIdx.x * N_DIM + tid * 8;
    *(float4*)p       = make_float4(a[0], a[1], a[2], a[3]);
    *(float4*)(p + 4) = make_float4(a[4], a[5], a[6], a[7]);
}

// ---------- k_cupd: u[j] = sum over NRB partials; c update (first=1: c_old=1) ----------
__global__ __launch_bounds__(256) void k_cupd(const float* __restrict__ partial,
                                              float* __restrict__ cvec, int first) {
    __shared__ float s[4][64];
    const int tc = threadIdx.x & 63;
    const int tg = threadIdx.x >> 6;
    const int j = blockIdx.x * 64 + tc;             // grid 128
    float u = 0.f;
    #pragma unroll 8
    for (int rb = tg * (NRB / 4); rb < (tg + 1) * (NRB / 4); ++rb)
        u += partial[(size_t)rb * N_DIM + j];
    s[tg][tc] = u;
    __syncthreads();
    if (threadIdx.x < 64) {
        const float tot = s[0][tc] + s[1][tc] + s[2][tc] + s[3][tc];
        const float cj = first ? 1.f : cvec[j];
        cvec[j] = cj / (cj * tot + EPS);
    }
}

// ---------- k_out: out[i][j] = bf16(B)[i][j] * r[i] * c[j] ----------
__global__ __launch_bounds__(256) void k_out(const unsigned short* __restrict__ B,
                                             const float* __restrict__ r,
                                             const float* __restrict__ cvec,
                                             float* __restrict__ out) {
    const int row = blockIdx.x;
    const float ri = r[row];
    const uint4* brow = (const uint4*)(B + (size_t)row * N_DIM);
    const float4* cv = (const float4*)cvec;
    float* orow = out + (size_t)row * N_DIM;
    #pragma unroll
    for (int it = 0; it < 4; ++it) {
        const int v = it * 256 + (int)threadIdx.x;
        const uint4 b = brow[v];
        const float4 c0 = cv[2 * v];
        const float4 c1 = cv[2 * v + 1];
        *(float4*)(orow + v * 8)     = make_float4(bflo(b.x) * ri * c0.x, bfhi(b.x) * ri * c0.y,
                                                   bflo(b.y) * ri * c0.z, bfhi(b.y) * ri * c0.w);
        *(float4*)(orow + v * 8 + 4) = make_float4(bflo(b.z) * ri * c1.x, bfhi(b.z) * ri * c1.y,
                                                   bflo(b.w) * ri * c1.z, bfhi(b.w) * ri * c1.w);
    }
}

// ---------- fallback k_out reading fp32 logits (used only if ws too small for B) ----------
__global__ __launch_bounds__(256) void k_out_logits(const float* __restrict__ logits,
                                                    const float* __restrict__ r,
                                                    const float* __restrict__ cvec,
                                                    float* __restrict__ out) {
    const int row = blockIdx.x;
    const float ri = r[row];
    const float4* lrow = (const float4*)(logits + (size_t)row * N_DIM);
    const float4* cv = (const float4*)cvec;
    float4* orow = (float4*)(out + (size_t)row * N_DIM);
    #pragma unroll
    for (int it = 0; it < 8; ++it) {
        const int v = it * 256 + (int)threadIdx.x;
        const float4 x = lrow[v];
        const float4 cc = cv[v];
        const int j = v * 4;
        float s0 = sigmoidf_fast(x.x); if (j     == row) s0 += 1.f;
        float s1 = sigmoidf_fast(x.y); if (j + 1 == row) s1 += 1.f;
        float s2 = sigmoidf_fast(x.z); if (j + 2 == row) s2 += 1.f;
        float s3 = sigmoidf_fast(x.w); if (j + 3 == row) s3 += 1.f;
        orow[v] = make_float4(s0 * ri * cc.x, s1 * ri * cc.y, s2 * ri * cc.z, s3 * ri * cc.w);
    }
}

extern "C" void kernel_launch(void* const* d_in, const int* in_sizes, int n_in,
                              void* d_out, int out_size, void* d_ws, size_t ws_size,
                              hipStream_t stream) {
    const float* logits = (const float*)d_in[0];
    float* out = (float*)d_out;
    const size_t nn = (size_t)N_DIM * N_DIM;
    // ws layout: B (128 MB bf16) | r | c | partial (NRB*N floats = 16 MB)
    const size_t need = nn * 2 + (2 * N_DIM + (size_t)NRB * N_DIM) * 4;
    const bool use_ws = ws_size >= need + 256;
    float* wsf = (float*)d_ws;
    unsigned short* B;
    float *r, *cvec, *partial;
    if (use_ws) {                                   // ws is 1 GiB in this harness
        B = (unsigned short*)wsf;
        r = wsf + nn / 2;
    } else {                                        // stash B in upper half of d_out
        B = (unsigned short*)(out + nn / 2);
        r = wsf;
    }
    cvec = r + N_DIM;
    partial = cvec + N_DIM;

    k_init<<<dim3(NRB), dim3(TPB), 0, stream>>>(logits, B, r, partial);
    k_cupd<<<dim3(128), dim3(256), 0, stream>>>(partial, cvec, 1);
    for (int it = 1; it < 5; ++it) {
        k_fused<<<dim3(NRB), dim3(TPB), 0, stream>>>(B, cvec, r, partial);
        k_cupd<<<dim3(128), dim3(256), 0, stream>>>(partial, cvec, 0);
    }
    if (use_ws)
        k_out<<<dim3(N_DIM), dim3(256), 0, stream>>>(B, r, cvec, out);
    else
        k_out_logits<<<dim3(N_DIM), dim3(256), 0, stream>>>(logits, r, cvec, out);
}

// Round 2
// 888.526 us; speedup vs baseline: 1.1723x; 1.1723x over previous
//
#include <hip/hip_runtime.h>

#define N_DIM 8192
#define EPS 1e-6f
#define R_STRIP 16                     // rows per block
#define HALF 8                         // rows per register-cached half-strip
#define NRB (N_DIM / R_STRIP)          // 512 row-strip blocks
#define TPB 1024                       // 16 waves: 1 uint4 (8 cols) per thread per row

typedef float f32x4v __attribute__((ext_vector_type(4)));

// ---------- bf16 helpers (bit-level) ----------
__device__ __forceinline__ float bflo(unsigned u) { return __uint_as_float(u << 16); }
__device__ __forceinline__ float bfhi(unsigned u) { return __uint_as_float(u & 0xffff0000u); }
__device__ __forceinline__ unsigned f2bf_bits(float f) {
    unsigned u = __float_as_uint(f);
    return (u + 0x7fffu + ((u >> 16) & 1u)) >> 16;   // round-to-nearest-even
}
__device__ __forceinline__ float sigmoidf_fast(float x) {
    return 1.f / (1.f + __expf(-x));
}
__device__ __forceinline__ float dot8(uint4 b, float4 c0, float4 c1) {
    return bflo(b.x) * c0.x + bfhi(b.x) * c0.y + bflo(b.y) * c0.z + bfhi(b.y) * c0.w
         + bflo(b.z) * c1.x + bfhi(b.z) * c1.y + bflo(b.w) * c1.z + bfhi(b.w) * c1.w;
}
__device__ __forceinline__ void acc8(float* a, uint4 b, float rr) {
    a[0] += bflo(b.x) * rr; a[1] += bfhi(b.x) * rr;
    a[2] += bflo(b.y) * rr; a[3] += bfhi(b.y) * rr;
    a[4] += bflo(b.z) * rr; a[5] += bfhi(b.z) * rr;
    a[6] += bflo(b.w) * rr; a[7] += bfhi(b.w) * rr;
}
// sigmoid+I, pack 8 to bf16, accumulate rounded sum into t
__device__ __forceinline__ uint4 sig_pack8(float4 x0, float4 x1, int jbase, int row, float& t) {
    float s[8] = { sigmoidf_fast(x0.x), sigmoidf_fast(x0.y), sigmoidf_fast(x0.z), sigmoidf_fast(x0.w),
                   sigmoidf_fast(x1.x), sigmoidf_fast(x1.y), sigmoidf_fast(x1.z), sigmoidf_fast(x1.w) };
    #pragma unroll
    for (int k = 0; k < 8; ++k)
        if (jbase + k == row) s[k] += 1.f;
    unsigned b[8];
    #pragma unroll
    for (int k = 0; k < 8; ++k) {
        b[k] = f2bf_bits(s[k]);
        t += __uint_as_float(b[k] << 16);          // sum the ROUNDED values
    }
    return make_uint4(b[0] | (b[1] << 16), b[2] | (b[3] << 16),
                      b[4] | (b[5] << 16), b[6] | (b[7] << 16));
}

// ---------- k_init: B = bf16(sigmoid+I); fused iteration-1 row norm + col partials ----------
// 1024 threads; two half-strips of 8 rows held in registers (no spill); 2 barriers per half.
__global__ __launch_bounds__(TPB, 4) void k_init(const float* __restrict__ logits,
                                                 unsigned short* __restrict__ B,
                                                 float* __restrict__ r,
                                                 float* __restrict__ partial) {
    __shared__ float sredT[16][HALF];               // [wave][row-in-half]
    __shared__ float rr[HALF];
    const int tid = threadIdx.x;
    const int lane = tid & 63, wid = tid >> 6;      // 16 waves
    const int i0 = blockIdx.x * R_STRIP;
    float a[8];
    #pragma unroll
    for (int k = 0; k < 8; ++k) a[k] = 0.f;

    for (int h = 0; h < 2; ++h) {
        const int rbase = i0 + h * HALF;
        uint4 b[HALF];
        float t[HALF];
        #pragma unroll
        for (int q = 0; q < HALF; ++q) {
            const int row = rbase + q;
            const f32x4v* l = (const f32x4v*)(logits + (size_t)row * N_DIM);
            const f32x4v xa = __builtin_nontemporal_load(l + 2 * tid);  // read-once
            const f32x4v xb = __builtin_nontemporal_load(l + 2 * tid + 1);
            float tl = 0.f;
            b[q] = sig_pack8(make_float4(xa.x, xa.y, xa.z, xa.w),
                             make_float4(xb.x, xb.y, xb.z, xb.w), tid * 8, row, tl);
            t[q] = tl;
            ((uint4*)(B + (size_t)row * N_DIM))[tid] = b[q];
        }
        #pragma unroll
        for (int off = 32; off > 0; off >>= 1)
            #pragma unroll
            for (int q = 0; q < HALF; ++q) t[q] += __shfl_xor(t[q], off, 64);
        if (lane == 0) {
            #pragma unroll
            for (int q = 0; q < HALF; ++q) sredT[wid][q] = t[q];
        }
        __syncthreads();
        if (tid < HALF) {
            float T = 0.f;
            #pragma unroll
            for (int w = 0; w < 16; ++w) T += sredT[w][tid];
            const float rv = 1.f / (T + EPS);       // r_old = 1
            rr[tid] = rv;
            r[rbase + tid] = rv;
        }
        __syncthreads();
        #pragma unroll
        for (int q = 0; q < HALF; ++q) acc8(a, b[q], rr[q]);
        // per-thread acc8 reads of rr precede (in program order) this thread's next-half
        // sredT write, and the next __syncthreads orders the next rr overwrite. Safe.
    }
    float* p = partial + (size_t)blockIdx.x * N_DIM + tid * 8;
    *(float4*)p       = make_float4(a[0], a[1], a[2], a[3]);
    *(float4*)(p + 4) = make_float4(a[4], a[5], a[6], a[7]);
}

// ---------- k_fused: one full iteration's row step + col partials, ONE pass over B ----------
__global__ __launch_bounds__(TPB, 4) void k_fused(const unsigned short* __restrict__ B,
                                                  const float* __restrict__ cvec,
                                                  float* __restrict__ r,
                                                  float* __restrict__ partial) {
    __shared__ float sredT[16][HALF];
    __shared__ float rr[HALF];
    const int tid = threadIdx.x;
    const int lane = tid & 63, wid = tid >> 6;
    const int i0 = blockIdx.x * R_STRIP;
    const float4 c0 = ((const float4*)cvec)[2 * tid];
    const float4 c1 = ((const float4*)cvec)[2 * tid + 1];
    const uint4* bp = (const uint4*)B + tid;
    float a[8];
    #pragma unroll
    for (int k = 0; k < 8; ++k) a[k] = 0.f;

    for (int h = 0; h < 2; ++h) {
        const int rbase = i0 + h * HALF;
        uint4 b[HALF];
        #pragma unroll
        for (int q = 0; q < HALF; ++q)
            b[q] = bp[(size_t)(rbase + q) << 10];   // row stride = 1024 uint4
        float t[HALF];
        #pragma unroll
        for (int q = 0; q < HALF; ++q) t[q] = dot8(b[q], c0, c1);
        #pragma unroll
        for (int off = 32; off > 0; off >>= 1)
            #pragma unroll
            for (int q = 0; q < HALF; ++q) t[q] += __shfl_xor(t[q], off, 64);
        if (lane == 0) {
            #pragma unroll
            for (int q = 0; q < HALF; ++q) sredT[wid][q] = t[q];
        }
        __syncthreads();
        if (tid < HALF) {
            float T = 0.f;
            #pragma unroll
            for (int w = 0; w < 16; ++w) T += sredT[w][tid];
            const float rold = r[rbase + tid];
            const float rv = rold / (rold * T + EPS);
            rr[tid] = rv;
            r[rbase + tid] = rv;
        }
        __syncthreads();
        #pragma unroll
        for (int q = 0; q < HALF; ++q) acc8(a, b[q], rr[q]);
    }
    float* p = partial + (size_t)blockIdx.x * N_DIM + tid * 8;
    *(float4*)p       = make_float4(a[0], a[1], a[2], a[3]);
    *(float4*)(p + 4) = make_float4(a[4], a[5], a[6], a[7]);
}

// ---------- k_cupd: u[j] = sum over NRB partials; c update (first=1: c_old=1) ----------
__global__ __launch_bounds__(256) void k_cupd(const float* __restrict__ partial,
                                              float* __restrict__ cvec, int first) {
    __shared__ float s[4][64];
    const int tc = threadIdx.x & 63;
    const int tg = threadIdx.x >> 6;
    const int j = blockIdx.x * 64 + tc;             // grid 128
    float u = 0.f;
    #pragma unroll 8
    for (int rb = tg * (NRB / 4); rb < (tg + 1) * (NRB / 4); ++rb)
        u += partial[(size_t)rb * N_DIM + j];
    s[tg][tc] = u;
    __syncthreads();
    if (threadIdx.x < 64) {
        const float tot = s[0][tc] + s[1][tc] + s[2][tc] + s[3][tc];
        const float cj = first ? 1.f : cvec[j];
        cvec[j] = cj / (cj * tot + EPS);
    }
}

// ---------- k_out: out[i][j] = bf16(B)[i][j] * r[i] * c[j] ----------
__global__ __launch_bounds__(256) void k_out(const unsigned short* __restrict__ B,
                                             const float* __restrict__ r,
                                             const float* __restrict__ cvec,
                                             float* __restrict__ out) {
    const int row = blockIdx.x;
    const float ri = r[row];
    const uint4* brow = (const uint4*)(B + (size_t)row * N_DIM);
    const float4* cv = (const float4*)cvec;
    float* orow = out + (size_t)row * N_DIM;
    #pragma unroll
    for (int it = 0; it < 4; ++it) {
        const int v = it * 256 + (int)threadIdx.x;
        const uint4 b = brow[v];
        const float4 c0 = cv[2 * v];
        const float4 c1 = cv[2 * v + 1];
        *(float4*)(orow + v * 8)     = make_float4(bflo(b.x) * ri * c0.x, bfhi(b.x) * ri * c0.y,
                                                   bflo(b.y) * ri * c0.z, bfhi(b.y) * ri * c0.w);
        *(float4*)(orow + v * 8 + 4) = make_float4(bflo(b.z) * ri * c1.x, bfhi(b.z) * ri * c1.y,
                                                   bflo(b.w) * ri * c1.z, bfhi(b.w) * ri * c1.w);
    }
}

// ---------- fallback k_out reading fp32 logits (used only if ws too small for B) ----------
__global__ __launch_bounds__(256) void k_out_logits(const float* __restrict__ logits,
                                                    const float* __restrict__ r,
                                                    const float* __restrict__ cvec,
                                                    float* __restrict__ out) {
    const int row = blockIdx.x;
    const float ri = r[row];
    const float4* lrow = (const float4*)(logits + (size_t)row * N_DIM);
    const float4* cv = (const float4*)cvec;
    float4* orow = (float4*)(out + (size_t)row * N_DIM);
    #pragma unroll
    for (int it = 0; it < 8; ++it) {
        const int v = it * 256 + (int)threadIdx.x;
        const float4 x = lrow[v];
        const float4 cc = cv[v];
        const int j = v * 4;
        float s0 = sigmoidf_fast(x.x); if (j     == row) s0 += 1.f;
        float s1 = sigmoidf_fast(x.y); if (j + 1 == row) s1 += 1.f;
        float s2 = sigmoidf_fast(x.z); if (j + 2 == row) s2 += 1.f;
        float s3 = sigmoidf_fast(x.w); if (j + 3 == row) s3 += 1.f;
        orow[v] = make_float4(s0 * ri * cc.x, s1 * ri * cc.y, s2 * ri * cc.z, s3 * ri * cc.w);
    }
}

extern "C" void kernel_launch(void* const* d_in, const int* in_sizes, int n_in,
                              void* d_out, int out_size, void* d_ws, size_t ws_size,
                              hipStream_t stream) {
    const float* logits = (const float*)d_in[0];
    float* out = (float*)d_out;
    const size_t nn = (size_t)N_DIM * N_DIM;
    // ws layout: B (128 MB bf16) | r | c | partial (NRB*N floats = 16 MB)
    const size_t need = nn * 2 + (2 * N_DIM + (size_t)NRB * N_DIM) * 4;
    const bool use_ws = ws_size >= need + 256;
    float* wsf = (float*)d_ws;
    unsigned short* B;
    float *r, *cvec, *partial;
    if (use_ws) {                                   // ws is 1 GiB in this harness
        B = (unsigned short*)wsf;
        r = wsf + nn / 2;
    } else {                                        // stash B in upper half of d_out
        B = (unsigned short*)(out + nn / 2);
        r = wsf;
    }
    cvec = r + N_DIM;
    partial = cvec + N_DIM;

    k_init<<<dim3(NRB), dim3(TPB), 0, stream>>>(logits, B, r, partial);
    k_cupd<<<dim3(128), dim3(256), 0, stream>>>(partial, cvec, 1);
    for (int it = 1; it < 5; ++it) {
        k_fused<<<dim3(NRB), dim3(TPB), 0, stream>>>(B, cvec, r, partial);
        k_cupd<<<dim3(128), dim3(256), 0, stream>>>(partial, cvec, 0);
    }
    if (use_ws)
        k_out<<<dim3(N_DIM), dim3(256), 0, stream>>>(B, r, cvec, out);
    else
        k_out_logits<<<dim3(N_DIM), dim3(256), 0, stream>>>(logits, r, cvec, out);
}